// Round 9
// baseline (104.864 us; speedup 1.0000x reference)
//
#include <hip/hip_runtime.h>
#include <hip/hip_bf16.h>

// MMD loss via bf16 MFMA Gram matrix.
// R9: TRUE deep pipeline — 4-slot LDS ring, issue-ahead = 4 chunks.
// R8 post-mortem: its "depth-2" waited each load batch one iteration after
// issue (~250cy cover vs ~900cy latency) -> no depth at all; explains why
// R5/R7/R8 were all neutral (every variant had <=1 chunk-period of cover).
// Now: prologue issues chunks 0-3 (16 glds/wave); chunk k waits vmcnt(N)
// (N=12,12,12,12,12,8,4,0: only chunk k's 4 oldest), barrier, ds_read, MFMA,
// barrier, then issues chunk k+4 into the freed slot. Load-to-use distance
// ~3.5 chunk-periods >= HBM latency. LDS 64KB exactly (wsum aliases bufA)
// -> 2 blocks/CU retained (R4 lesson: keep TLP). XCD-bijective swizzle
// (2080 = 8*260): same-panel blocks share an XCD L2 -> B-panel reuse.
//
// Zc layout: Zc[ck][row][32], stored quad = q ^ ((row>>1)&3); 128-row panel
// per chunk = contiguous 8KB; supertile base % 128 == 0 keeps the swizzle
// valid on LDS-local rows. glds: wave-uniform LDS base + lane*16B.
// Lessons: no __threadfence; no scattered vector loads; no s_barrier
// alignment of reg streams (R3); no 1 wave/SIMD (R4); shallow prefetch of
// any flavor is neutral (R5/R7/R8).
//
// z = [xf; yf] (8192 x 256). result = (1/4096^2)*(8192*NSIG + sum_{i<j} 2 s_i s_j K_ij)
// ws: [0,4MiB) bf16 Zc; float norms[8192]; float partials[2080].

#define NSIG 5
#define CKS   262144                 // chunk stride in ushorts: 8192 rows * 32
#define NBLK2 2080                   // 64-supergrid triangle: 64*65/2

typedef __attribute__((ext_vector_type(8))) short short8;
typedef __attribute__((ext_vector_type(4))) float floatx4;

#define GLDS16(gp, lp) __builtin_amdgcn_global_load_lds( \
    (const __attribute__((address_space(1))) void*)(gp),  \
    (__attribute__((address_space(3))) void*)(lp), 16, 0, 0)

// ---- prep: (B,C,H,W) fp32 -> Zc chunked-swizzled bf16 + norms (unchanged) ----
__global__ __launch_bounds__(256) void prep_kernel(const float* __restrict__ x,
                                                   const float* __restrict__ y,
                                                   ushort* __restrict__ Zc,
                                                   float* __restrict__ norms) {
    const int bid = blockIdx.x;           // s(1) | b(2) | strip(6)
    const int t = threadIdx.x;
    const int s = bid >> 8;
    const int b = (bid >> 6) & 3;
    const int p0 = (bid & 63) << 4;
    const float* src = s ? y : x;
    const int n0 = (s << 12) + (b << 10) + p0;

    __shared__ float tile[256][17];

    const int cg = t >> 2;
    const int p4 = (t & 3) << 2;
#pragma unroll
    for (int pass = 0; pass < 4; ++pass) {
        const int c = cg + (pass << 6);
        const float4 v = *(const float4*)(src + (((size_t)((b << 8) + c)) << 10) + p0 + p4);
        tile[c][p4] = v.x; tile[c][p4 + 1] = v.y; tile[c][p4 + 2] = v.z; tile[c][p4 + 3] = v.w;
    }
    __syncthreads();

    const int r = t >> 4;
    const int q = t & 15;
    const int row = n0 + r;
    const int sw = (row >> 1) & 3;
    float nsum = 0.f;
#pragma unroll
    for (int h = 0; h < 2; ++h) {
        const int j = q + (h << 4);
        const int ck = j >> 2;
        const int sq = (j & 3) ^ sw;
        const int c0 = j << 3;
        uint pk[4];
#pragma unroll
        for (int jj = 0; jj < 4; ++jj) {
            const float f0 = tile[c0 + 2 * jj][r];
            const float f1 = tile[c0 + 2 * jj + 1][r];
            const __hip_bfloat16 h0 = __float2bfloat16(f0);
            const __hip_bfloat16 h1 = __float2bfloat16(f1);
            const float q0 = __bfloat162float(h0), q1 = __bfloat162float(h1);
            nsum = fmaf(q0, q0, nsum);
            nsum = fmaf(q1, q1, nsum);
            pk[jj] = (uint)(*(const ushort*)&h0) | ((uint)(*(const ushort*)&h1) << 16);
        }
        *(uint4*)(Zc + (size_t)ck * CKS + (size_t)row * 32 + (sq << 3)) =
            make_uint4(pk[0], pk[1], pk[2], pk[3]);
    }
#pragma unroll
    for (int off = 1; off < 16; off <<= 1) nsum += __shfl_xor(nsum, off, 32);
    if (q == 0) norms[row] = nsum;
}

// ---- GEMM: 4-wave blocks, 128x128 supertile, 4-slot ring deep pipeline ----
__global__ __launch_bounds__(256, 2) void gemm_epi(const ushort* __restrict__ Zc,
                                                   const float* __restrict__ norms,
                                                   const float* __restrict__ sigmas,
                                                   float* __restrict__ partials) {
    __shared__ ushort bufA[4][4096];   // 4 x 8KB ring: A panel (128 rows x 32)
    __shared__ ushort bufB[4][4096];   // 4 x 8KB ring: B panel   (total 64KB)

    const int t = threadIdx.x;
    const int w = t >> 6, l = t & 63;
    const int m = l & 15, q = l >> 4;

    // XCD-bijective swizzle: 2080 = 8*260, consecutive panel-order -> same XCD
    const int bid = blockIdx.x;
    const int lin = (bid & 7) * 260 + (bid >> 3);

    // panel decode: panels p of 8 super-columns; P(p) = 32p^2 + 4p blocks before
    // panel p; within panel, column-major (column tj2 has tj2+1 blocks).
    int p = (int)((-4.0f + sqrtf(16.0f + 128.0f * (float)lin)) * (1.0f / 64.0f));
    p = p < 0 ? 0 : (p > 7 ? 7 : p);
    while (p < 7 && 32 * (p + 1) * (p + 1) + 4 * (p + 1) <= lin) ++p;
    while (p > 0 && 32 * p * p + 4 * p > lin) --p;
    const int o = lin - (32 * p * p + 4 * p);
    int c = 7;
#pragma unroll
    for (int cc = 7; cc >= 1; --cc) {
        const int Q = cc * (8 * p + 1) + (cc * (cc - 1)) / 2;
        if (o < Q) c = cc - 1;
    }
    const int Qc = c * (8 * p + 1) + (c * (c - 1)) / 2;
    const int tj2 = 8 * p + c;
    const int ti2 = o - Qc;              // 0..tj2

    const int I0 = ti2 << 7;             // supertile bases (multiples of 128)
    const int J0 = tj2 << 7;

    // wave quadrant: ti = 2*ti2 + (w>>1), tj = 2*tj2 + (w&1)
    const int ti = (ti2 << 1) + (w >> 1);
    const int tj = (tj2 << 1) + (w & 1);
    const bool active = (ti <= tj);      // lower-tri wave of diag supertile: discard
    const bool diag = (ti == tj);
    const int i0 = ti << 6, j0 = tj << 6;

    // LDS fragment read offsets (ushort idx, panel-local rows)
    int loffA[4], loffB[4];
#pragma unroll
    for (int f = 0; f < 4; ++f) {
        const int ra = ((w >> 1) << 6) + (f << 4) + m;
        loffA[f] = (ra << 5) + ((q ^ ((ra >> 1) & 3)) << 3);
        const int rb = ((w & 1) << 6) + (f << 4) + m;
        loffB[f] = (rb << 5) + ((q ^ ((rb >> 1) & 3)) << 3);
    }

    // staging: wave w copies ushorts [w*1024,(w+1)*1024) of each 8KB panel,
    // 2 glds per panel (lane offset = lane*16B, HW-linear). 4 glds/wave/chunk.
    const int sg = (w << 10) + (l << 3);
    const ushort* gA0 = Zc + (size_t)I0 * 32 + sg;
    const ushort* gB0 = Zc + (size_t)J0 * 32 + sg;
    const int lo = w << 10;

#define STAGE(k) do {                                                   \
        const size_t ko_ = (size_t)(k) * CKS; const int s_ = (k) & 3;   \
        GLDS16(gA0 + ko_,       &bufA[s_][lo]);                         \
        GLDS16(gA0 + ko_ + 512, &bufA[s_][lo + 512]);                   \
        GLDS16(gB0 + ko_,       &bufB[s_][lo]);                         \
        GLDS16(gB0 + ko_ + 512, &bufB[s_][lo + 512]);                   \
    } while (0)

    // prologue: issue chunks 0-3 (16 glds in flight per wave)
    STAGE(0); STAGE(1); STAGE(2); STAGE(3);

    floatx4 accf[4][4];
#pragma unroll
    for (int fi = 0; fi < 4; ++fi)
#pragma unroll
        for (int fj = 0; fj < 4; ++fj) accf[fi][fj] = (floatx4){0.f, 0.f, 0.f, 0.f};

#define CHUNK(k, N) do {                                                 \
        asm volatile("s_waitcnt vmcnt(" #N ")" ::: "memory");            \
        __builtin_amdgcn_s_barrier();                                    \
        __builtin_amdgcn_sched_barrier(0);                               \
        const ushort* rA_ = &bufA[(k) & 3][0];                           \
        const ushort* rB_ = &bufB[(k) & 3][0];                           \
        short8 fa_[4], fb_[4];                                           \
        _Pragma("unroll")                                                \
        for (int f = 0; f < 4; ++f) fa_[f] = *(const short8*)(rA_ + loffA[f]); \
        _Pragma("unroll")                                                \
        for (int f = 0; f < 4; ++f) fb_[f] = *(const short8*)(rB_ + loffB[f]); \
        _Pragma("unroll")                                                \
        for (int fi = 0; fi < 4; ++fi)                                   \
            _Pragma("unroll")                                            \
            for (int fj = 0; fj < 4; ++fj)                               \
                accf[fi][fj] = __builtin_amdgcn_mfma_f32_16x16x32_bf16(  \
                    fa_[fi], fb_[fj], accf[fi][fj], 0, 0, 0);            \
        __builtin_amdgcn_s_barrier();                                    \
        __builtin_amdgcn_sched_barrier(0);                               \
        if ((k) + 4 < 8) STAGE((k) + 4);                                 \
    } while (0)

    // wait schedule: chunk k needs its 4 oldest loads retired.
    CHUNK(0, 12); CHUNK(1, 12); CHUNK(2, 12); CHUNK(3, 12);
    CHUNK(4, 12); CHUNK(5, 8);  CHUNK(6, 4);  CHUNK(7, 0);

#undef CHUNK
#undef STAGE

    // ---- epilogue (no barriers until final reduce) ----
    float lsum = 0.f;
    if (active) {
        float c2[NSIG];
#pragma unroll
        for (int k = 0; k < NSIG; ++k) c2[k] = (-0.5f / sigmas[k]) * 1.44269504f;

        const float sgn2 = ((i0 < 4096) == (j0 < 4096)) ? 2.f : -2.f;

        float njs[4];
#pragma unroll
        for (int fj = 0; fj < 4; ++fj) njs[fj] = norms[j0 + (fj << 4) + m];

#pragma unroll
        for (int fi = 0; fi < 4; ++fi) {
            const floatx4 ni4 = *(const floatx4*)(norms + i0 + (fi << 4) + (q << 2));
#pragma unroll
            for (int fj = 0; fj < 4; ++fj) {
#pragma unroll
                for (int v = 0; v < 4; ++v) {
                    float d = fmaf(-2.f, accf[fi][fj][v], ni4[v] + njs[fj]);
                    d = fmaxf(d, 0.f);
                    if (diag) {
                        const int dif = ((fi - fj) << 4) + ((q << 2) + v) - m;   // gi - gj
                        d = (dif < 0) ? d : 3.0e9f;    // strictly-upper only
                    }
                    accf[fi][fj][v] = d;
                }
            }
        }

        float dmin = accf[0][0][0];
#pragma unroll
        for (int fi = 0; fi < 4; ++fi)
#pragma unroll
            for (int fj = 0; fj < 4; ++fj)
#pragma unroll
                for (int v = 0; v < 4; ++v) dmin = fminf(dmin, accf[fi][fj][v]);
#pragma unroll
        for (int off = 1; off < 64; off <<= 1) dmin = fminf(dmin, __shfl_xor(dmin, off, 64));

        float tsum = 0.f;
#pragma unroll
        for (int k = 0; k < NSIG; ++k) {
            if (c2[k] * dmin >= -126.f) {   // wave-uniform skip iff all exps underflow
#pragma unroll
                for (int fi = 0; fi < 4; ++fi)
#pragma unroll
                    for (int fj = 0; fj < 4; ++fj)
#pragma unroll
                        for (int v = 0; v < 4; ++v)
                            tsum += __builtin_amdgcn_exp2f(c2[k] * accf[fi][fj][v]);
            }
        }
        lsum = sgn2 * tsum;
    }

    // ---- block reduce + store (wsum aliases bufA: LDS stays exactly 64KB) ----
#pragma unroll
    for (int off = 32; off > 0; off >>= 1) lsum += __shfl_down(lsum, off, 64);
    __syncthreads();                       // all LDS traffic drained
    float* wsum = (float*)&bufA[0][0];
    if (l == 0) wsum[w] = lsum;
    __syncthreads();
    if (t == 0) partials[bid] = wsum[0] + wsum[1] + wsum[2] + wsum[3];
}

__global__ __launch_bounds__(256) void finalize_kernel(const float* __restrict__ partials,
                                                       float* __restrict__ out) {
    __shared__ double sh[256];
    const int t = threadIdx.x;
    double s = 0.0;
    for (int i = t; i < NBLK2; i += 256) s += (double)partials[i];
    sh[t] = s;
    __syncthreads();
    for (int st = 128; st > 0; st >>= 1) {
        if (t < st) sh[t] += sh[t + st];
        __syncthreads();
    }
    if (t == 0) out[0] = (float)((sh[0] + 8192.0 * NSIG) * (1.0 / (4096.0 * 4096.0)));
}

extern "C" void kernel_launch(void* const* d_in, const int* in_sizes, int n_in,
                              void* d_out, int out_size, void* d_ws, size_t ws_size,
                              hipStream_t stream) {
    const float* x   = (const float*)d_in[0];
    const float* y   = (const float*)d_in[1];
    const float* sig = (const float*)d_in[2];

    ushort* Zc      = (ushort*)d_ws;                                   // 4 MiB
    float* norms    = (float*)((char*)d_ws + (size_t)8192 * 256 * 2);  // 32 KiB
    float* partials = (float*)((char*)norms + 8192 * sizeof(float));   // 2080 floats
    float* out      = (float*)d_out;

    prep_kernel<<<512, 256, 0, stream>>>(x, y, Zc, norms);
    gemm_epi<<<NBLK2, 256, 0, stream>>>(Zc, norms, sig, partials);
    finalize_kernel<<<1, 256, 0, stream>>>(partials, out);
}

// Round 10
// 94.608 us; speedup vs baseline: 1.1084x; 1.1084x over previous
//
#include <hip/hip_runtime.h>
#include <hip/hip_bf16.h>

// MMD loss via bf16 MFMA Gram matrix.
// R10: R8 K-loop (best measured: 3-buffer LDS ring, counted vmcnt, one raw
// barrier per chunk) + epilogue restructure. Counters said VALUBusy 31.6% >>
// MfmaUtil 13.3% since R1; epilogue had serial fp chains (256-add tsum =
// 1024cy, 127-fmin dmin = 508cy dependency latency) the compiler can't
// reassociate without fast-math. Now: 8 independent accumulation chains
// (two floatx4), component-parallel dmin + tree, vector-shaped d-compute
// (invites v_pk_fma/max), diag mask hoisted to wave-uniform branch.
// R9 lesson: depth-4 ring + 2 barriers/chunk + 64KB LDS REGRESSED (+9us);
// pipeline family exhausted (R5/R7/R8/R9: traffic -50%, depth 1..4,
// occupancy 1..3 blk/CU all within +-10%).
//
// Zc layout: Zc[ck][row][32], stored quad = q ^ ((row>>1)&3); 128-row panel
// per chunk = contiguous 8KB; supertile base % 128 == 0 keeps the swizzle
// valid on LDS-local rows. glds: wave-uniform LDS base + lane*16B.
//
// z = [xf; yf] (8192 x 256). result = (1/4096^2)*(8192*NSIG + sum_{i<j} 2 s_i s_j K_ij)
// ws: [0,4MiB) bf16 Zc; float norms[8192]; float partials[2080].

#define NSIG 5
#define CKS   262144                 // chunk stride in ushorts: 8192 rows * 32
#define NBLK2 2080                   // 64-supergrid triangle: 64*65/2

typedef __attribute__((ext_vector_type(8))) short short8;
typedef __attribute__((ext_vector_type(4))) float floatx4;

#define GLDS16(gp, lp) __builtin_amdgcn_global_load_lds( \
    (const __attribute__((address_space(1))) void*)(gp),  \
    (__attribute__((address_space(3))) void*)(lp), 16, 0, 0)

// ---- prep: (B,C,H,W) fp32 -> Zc chunked-swizzled bf16 + norms (unchanged) ----
__global__ __launch_bounds__(256) void prep_kernel(const float* __restrict__ x,
                                                   const float* __restrict__ y,
                                                   ushort* __restrict__ Zc,
                                                   float* __restrict__ norms) {
    const int bid = blockIdx.x;           // s(1) | b(2) | strip(6)
    const int t = threadIdx.x;
    const int s = bid >> 8;
    const int b = (bid >> 6) & 3;
    const int p0 = (bid & 63) << 4;
    const float* src = s ? y : x;
    const int n0 = (s << 12) + (b << 10) + p0;

    __shared__ float tile[256][17];

    const int cg = t >> 2;
    const int p4 = (t & 3) << 2;
#pragma unroll
    for (int pass = 0; pass < 4; ++pass) {
        const int c = cg + (pass << 6);
        const float4 v = *(const float4*)(src + (((size_t)((b << 8) + c)) << 10) + p0 + p4);
        tile[c][p4] = v.x; tile[c][p4 + 1] = v.y; tile[c][p4 + 2] = v.z; tile[c][p4 + 3] = v.w;
    }
    __syncthreads();

    const int r = t >> 4;
    const int q = t & 15;
    const int row = n0 + r;
    const int sw = (row >> 1) & 3;
    float nsum = 0.f;
#pragma unroll
    for (int h = 0; h < 2; ++h) {
        const int j = q + (h << 4);
        const int ck = j >> 2;
        const int sq = (j & 3) ^ sw;
        const int c0 = j << 3;
        uint pk[4];
#pragma unroll
        for (int jj = 0; jj < 4; ++jj) {
            const float f0 = tile[c0 + 2 * jj][r];
            const float f1 = tile[c0 + 2 * jj + 1][r];
            const __hip_bfloat16 h0 = __float2bfloat16(f0);
            const __hip_bfloat16 h1 = __float2bfloat16(f1);
            const float q0 = __bfloat162float(h0), q1 = __bfloat162float(h1);
            nsum = fmaf(q0, q0, nsum);
            nsum = fmaf(q1, q1, nsum);
            pk[jj] = (uint)(*(const ushort*)&h0) | ((uint)(*(const ushort*)&h1) << 16);
        }
        *(uint4*)(Zc + (size_t)ck * CKS + (size_t)row * 32 + (sq << 3)) =
            make_uint4(pk[0], pk[1], pk[2], pk[3]);
    }
#pragma unroll
    for (int off = 1; off < 16; off <<= 1) nsum += __shfl_xor(nsum, off, 32);
    if (q == 0) norms[row] = nsum;
}

// ---- GEMM: 4-wave blocks, 128x128 supertile, 3-buffer counted-vmcnt pipe ----
__global__ __launch_bounds__(256) void gemm_epi(const ushort* __restrict__ Zc,
                                                const float* __restrict__ norms,
                                                const float* __restrict__ sigmas,
                                                float* __restrict__ partials) {
    __shared__ ushort bufA[3][4096];   // 3 x 8KB: A panel (128 rows x 32)
    __shared__ ushort bufB[3][4096];   // 3 x 8KB: B panel
    __shared__ float wsum[4];

    const int t = threadIdx.x;
    const int w = t >> 6, l = t & 63;
    const int m = l & 15, q = l >> 4;

    // panel decode: panels p of 8 super-columns; P(p) = 32p^2 + 4p blocks before
    // panel p; within panel, column-major (column tj2 has tj2+1 blocks).
    const int lin = blockIdx.x;
    int p = (int)((-4.0f + sqrtf(16.0f + 128.0f * (float)lin)) * (1.0f / 64.0f));
    p = p < 0 ? 0 : (p > 7 ? 7 : p);
    while (p < 7 && 32 * (p + 1) * (p + 1) + 4 * (p + 1) <= lin) ++p;
    while (p > 0 && 32 * p * p + 4 * p > lin) --p;
    const int o = lin - (32 * p * p + 4 * p);
    int c = 7;
#pragma unroll
    for (int cc = 7; cc >= 1; --cc) {
        const int Q = cc * (8 * p + 1) + (cc * (cc - 1)) / 2;
        if (o < Q) c = cc - 1;
    }
    const int Qc = c * (8 * p + 1) + (c * (c - 1)) / 2;
    const int tj2 = 8 * p + c;
    const int ti2 = o - Qc;              // 0..tj2

    const int I0 = ti2 << 7;             // supertile bases (multiples of 128)
    const int J0 = tj2 << 7;

    // wave quadrant: ti = 2*ti2 + (w>>1), tj = 2*tj2 + (w&1)
    const int ti = (ti2 << 1) + (w >> 1);
    const int tj = (tj2 << 1) + (w & 1);
    const bool active = (ti <= tj);      // lower-tri wave of diag supertile: discard
    const bool diag = (ti == tj);
    const int i0 = ti << 6, j0 = tj << 6;

    // LDS fragment read offsets (ushort idx, panel-local rows)
    int loffA[4], loffB[4];
#pragma unroll
    for (int f = 0; f < 4; ++f) {
        const int ra = ((w >> 1) << 6) + (f << 4) + m;
        loffA[f] = (ra << 5) + ((q ^ ((ra >> 1) & 3)) << 3);
        const int rb = ((w & 1) << 6) + (f << 4) + m;
        loffB[f] = (rb << 5) + ((q ^ ((rb >> 1) & 3)) << 3);
    }

    // staging: wave w copies ushorts [w*1024, (w+1)*1024) of each 8KB panel,
    // two glds issues each (lane offset = lane*16B, HW-linear).
    const int sg = (w << 10) + (l << 3);
    const ushort* gA0 = Zc + (size_t)I0 * 32 + sg;
    const ushort* gB0 = Zc + (size_t)J0 * 32 + sg;
    const int lo = w << 10;

    // prologue: stage ck0 -> buf0 (oldest 4), ck1 -> buf1; wait ck0 only.
    GLDS16(gA0,        &bufA[0][lo]);
    GLDS16(gA0 + 512,  &bufA[0][lo + 512]);
    GLDS16(gB0,        &bufB[0][lo]);
    GLDS16(gB0 + 512,  &bufB[0][lo + 512]);
    GLDS16(gA0 + CKS,       &bufA[1][lo]);
    GLDS16(gA0 + CKS + 512, &bufA[1][lo + 512]);
    GLDS16(gB0 + CKS,       &bufB[1][lo]);
    GLDS16(gB0 + CKS + 512, &bufB[1][lo + 512]);
    asm volatile("s_waitcnt vmcnt(4)" ::: "memory");
    __builtin_amdgcn_s_barrier();
    __builtin_amdgcn_sched_barrier(0);

    floatx4 accf[4][4];
#pragma unroll
    for (int fi = 0; fi < 4; ++fi)
#pragma unroll
        for (int fj = 0; fj < 4; ++fj) accf[fi][fj] = (floatx4){0.f, 0.f, 0.f, 0.f};

    // ---- main K loop: 8 chunks, depth-2 glds, counted vmcnt, raw barrier ----
#pragma unroll
    for (int ck = 0; ck < 8; ++ck) {
        const ushort* rA = &bufA[ck % 3][0];
        const ushort* rB = &bufB[ck % 3][0];
        short8 fa[4], fb[4];
#pragma unroll
        for (int f = 0; f < 4; ++f) fa[f] = *(const short8*)(rA + loffA[f]);
#pragma unroll
        for (int f = 0; f < 4; ++f) fb[f] = *(const short8*)(rB + loffB[f]);
        if (ck < 6) {
            const size_t ko = (size_t)(ck + 2) * CKS;
            const int nb = (ck + 2) % 3;
            GLDS16(gA0 + ko,       &bufA[nb][lo]);
            GLDS16(gA0 + ko + 512, &bufA[nb][lo + 512]);
            GLDS16(gB0 + ko,       &bufB[nb][lo]);
            GLDS16(gB0 + ko + 512, &bufB[nb][lo + 512]);
        }
#pragma unroll
        for (int fi = 0; fi < 4; ++fi)
#pragma unroll
            for (int fj = 0; fj < 4; ++fj)
                accf[fi][fj] = __builtin_amdgcn_mfma_f32_16x16x32_bf16(fa[fi], fb[fj], accf[fi][fj], 0, 0, 0);
        if (ck < 7) {
            if (ck < 6) { asm volatile("s_waitcnt vmcnt(4)" ::: "memory"); }
            else        { asm volatile("s_waitcnt vmcnt(0)" ::: "memory"); }
            __builtin_amdgcn_s_barrier();
            __builtin_amdgcn_sched_barrier(0);
        }
    }

    // ---- epilogue: chain-parallel, vector-shaped (R10) ----
    float lsum = 0.f;
    if (active) {
        float c2[NSIG];
#pragma unroll
        for (int k = 0; k < NSIG; ++k) c2[k] = (-0.5f / sigmas[k]) * 1.44269504f;

        const float sgn2 = ((i0 < 4096) == (j0 < 4096)) ? 2.f : -2.f;

        float njs[4];
#pragma unroll
        for (int fj = 0; fj < 4; ++fj) njs[fj] = norms[j0 + (fj << 4) + m];

        // d = max(ni + nj - 2*g, 0) — vector-shaped, no per-element branch
#pragma unroll
        for (int fi = 0; fi < 4; ++fi) {
            const floatx4 ni4 = *(const floatx4*)(norms + i0 + (fi << 4) + (q << 2));
#pragma unroll
            for (int fj = 0; fj < 4; ++fj) {
                floatx4 a = accf[fi][fj];
#pragma unroll
                for (int v = 0; v < 4; ++v)
                    a[v] = fmaxf(fmaf(-2.f, a[v], ni4[v] + njs[fj]), 0.f);
                accf[fi][fj] = a;
            }
        }
        if (diag) {        // wave-uniform rare path: strictly-upper mask
#pragma unroll
            for (int fi = 0; fi < 4; ++fi)
#pragma unroll
                for (int fj = 0; fj < 4; ++fj)
#pragma unroll
                    for (int v = 0; v < 4; ++v) {
                        const int dif = ((fi - fj) << 4) + ((q << 2) + v) - m;   // gi - gj
                        if (dif >= 0) accf[fi][fj][v] = 3.0e9f;
                    }
        }

        // dmin: 4 independent component chains, then 2-level tree + shfl
        floatx4 mn = accf[0][0];
#pragma unroll
        for (int fi = 0; fi < 4; ++fi)
#pragma unroll
            for (int fj = 0; fj < 4; ++fj)
                if (fi | fj) {
#pragma unroll
                    for (int v = 0; v < 4; ++v) mn[v] = fminf(mn[v], accf[fi][fj][v]);
                }
        float dmin = fminf(fminf(mn[0], mn[1]), fminf(mn[2], mn[3]));
#pragma unroll
        for (int off = 1; off < 64; off <<= 1) dmin = fminf(dmin, __shfl_xor(dmin, off, 64));

        // exp accumulate: 8 independent chains (two floatx4 accumulators)
        floatx4 ts0 = (floatx4){0.f, 0.f, 0.f, 0.f};
        floatx4 ts1 = (floatx4){0.f, 0.f, 0.f, 0.f};
#pragma unroll
        for (int k = 0; k < NSIG; ++k) {
            if (c2[k] * dmin >= -126.f) {   // wave-uniform skip iff all exps underflow
                const float ck2 = c2[k];
#pragma unroll
                for (int fi = 0; fi < 4; ++fi)
#pragma unroll
                    for (int fj = 0; fj < 4; ++fj) {
                        const floatx4 a = accf[fi][fj];
                        floatx4 e;
#pragma unroll
                        for (int v = 0; v < 4; ++v)
                            e[v] = __builtin_amdgcn_exp2f(ck2 * a[v]);
                        if ((fj & 1) == 0) ts0 += e; else ts1 += e;
                    }
            }
        }
        ts0 += ts1;
        lsum = sgn2 * ((ts0[0] + ts0[1]) + (ts0[2] + ts0[3]));
    }

    // ---- block reduce + store ----
#pragma unroll
    for (int off = 32; off > 0; off >>= 1) lsum += __shfl_down(lsum, off, 64);
    if (l == 0) wsum[w] = lsum;
    __syncthreads();
    if (t == 0) partials[blockIdx.x] = wsum[0] + wsum[1] + wsum[2] + wsum[3];
}

__global__ __launch_bounds__(256) void finalize_kernel(const float* __restrict__ partials,
                                                       float* __restrict__ out) {
    __shared__ double sh[256];
    const int t = threadIdx.x;
    double s = 0.0;
    for (int i = t; i < NBLK2; i += 256) s += (double)partials[i];
    sh[t] = s;
    __syncthreads();
    for (int st = 128; st > 0; st >>= 1) {
        if (t < st) sh[t] += sh[t + st];
        __syncthreads();
    }
    if (t == 0) out[0] = (float)((sh[0] + 8192.0 * NSIG) * (1.0 / (4096.0 * 4096.0)));
}

extern "C" void kernel_launch(void* const* d_in, const int* in_sizes, int n_in,
                              void* d_out, int out_size, void* d_ws, size_t ws_size,
                              hipStream_t stream) {
    const float* x   = (const float*)d_in[0];
    const float* y   = (const float*)d_in[1];
    const float* sig = (const float*)d_in[2];

    ushort* Zc      = (ushort*)d_ws;                                   // 4 MiB
    float* norms    = (float*)((char*)d_ws + (size_t)8192 * 256 * 2);  // 32 KiB
    float* partials = (float*)((char*)norms + 8192 * sizeof(float));   // 2080 floats
    float* out      = (float*)d_out;

    prep_kernel<<<512, 256, 0, stream>>>(x, y, Zc, norms);
    gemm_epi<<<NBLK2, 256, 0, stream>>>(Zc, norms, sig, partials);
    finalize_kernel<<<1, 256, 0, stream>>>(partials, out);
}